// Round 6
// baseline (122.082 us; speedup 1.0000x reference)
//
#include <hip/hip_runtime.h>

#define N_NODES 50000
#define N_PAD   50048        // padded node count (tail block reads, store guarded)
#define N_EDGES 600000
#define IN_F 128
#define HID 256
#define OUT_F 64
#define ROWS 32              // nodes per block; 1563 blocks (tail guarded)
#define SLOTS 56             // fixed bucket slots/node; P(deg>=56|Poisson(12))~1e-24
#define NBLK ((N_NODES + ROWS - 1) / ROWS)

typedef __attribute__((ext_vector_type(8))) short bf16x8;
typedef __attribute__((ext_vector_type(4))) float f32x4;

__device__ inline short f2bf(float f) {   // RNE float->bf16 bits
    unsigned u = __builtin_bit_cast(unsigned, f);
    u += 0x7fffu + ((u >> 16) & 1u);
    return (short)(u >> 16);
}
__device__ inline float bflo(unsigned u) { return __builtin_bit_cast(float, u << 16); }
__device__ inline float bfhi(unsigned u) { return __builtin_bit_cast(float, u & 0xffff0000u); }

// ---------------------------------------------------------------------------
// prep+build (one kernel, disjoint block ranges; cursor pre-zeroed by memset):
//   [0,3125)      x fp32 -> bf16
//   [3125,3181)   weights fp32 [K][N] -> bf16 B-fragment-major 16B chunks
//   [3181,5525)   bucket fill: esrc[dst*56 + p] = src, cursor ends as deg
// ---------------------------------------------------------------------------
__global__ __launch_bounds__(256) void prep_build_kernel(
    const float* __restrict__ x, short* __restrict__ xb,
    const float* __restrict__ Wsg, const float* __restrict__ W1a,
    const float* __restrict__ W1b, const float* __restrict__ W2a,
    const float* __restrict__ W2b,
    short* __restrict__ Fsg, short* __restrict__ F1a, short* __restrict__ F1b,
    short* __restrict__ F2a, short* __restrict__ F2b,
    const int* __restrict__ ei, int* __restrict__ cursor, int* __restrict__ esrc)
{
    const int bid = blockIdx.x, t = threadIdx.x;
    if (bid < 3125) {
        int i = bid * 256 + t;                       // < 800000 exactly
        float4 a0 = *reinterpret_cast<const float4*>(x + (size_t)i * 8);
        float4 a1 = *reinterpret_cast<const float4*>(x + (size_t)i * 8 + 4);
        bf16x8 v;
        v[0] = f2bf(a0.x); v[1] = f2bf(a0.y); v[2] = f2bf(a0.z); v[3] = f2bf(a0.w);
        v[4] = f2bf(a1.x); v[5] = f2bf(a1.y); v[6] = f2bf(a1.z); v[7] = f2bf(a1.w);
        *reinterpret_cast<bf16x8*>(xb + (size_t)i * 8) = v;
    } else if (bid < 3181) {
        // chunk c: lane=c&63, ks=(c>>6)%KST, nt=(c>>6)/KST;
        //   elem j: B[ks*32 + (lane>>4)*8 + j][nt*16 + (lane&15)]
        int cid = (bid - 3125) * 256 + t;            // < 14336 exactly
        const float* src; short* dst; int N, KST, base;
        if      (cid < 2048)  { src = Wsg; dst = Fsg; N = 128; KST = 4; base = 0; }
        else if (cid < 6144)  { src = W1a; dst = F1a; N = 256; KST = 4; base = 2048; }
        else if (cid < 8192)  { src = W1b; dst = F1b; N = 64;  KST = 8; base = 6144; }
        else if (cid < 12288) { src = W2a; dst = F2a; N = 256; KST = 4; base = 8192; }
        else                  { src = W2b; dst = F2b; N = 64;  KST = 8; base = 12288; }
        int c = cid - base;
        int lane = c & 63;
        int rem = c >> 6;
        int ks = rem % KST;
        int nt = rem / KST;
        int col = nt * 16 + (lane & 15);
        int k0 = ks * 32 + (lane >> 4) * 8;
        bf16x8 v;
        #pragma unroll
        for (int j = 0; j < 8; ++j)
            v[j] = f2bf(src[(size_t)(k0 + j) * N + col]);
        *reinterpret_cast<bf16x8*>(dst + (size_t)c * 8) = v;
    } else {
        int e = (bid - 3181) * 256 + t;
        if (e < N_EDGES) {
            int src = ei[e];
            int dst = ei[N_EDGES + e];
            int p = atomicAdd(&cursor[dst], 1);
            if (p < SLOTS) esrc[(size_t)dst * SLOTS + p] = src;
        }
    }
}

// ---------------------------------------------------------------------------
// Stage1: Hs = relu(A @ Wa + ba), A-frags for both 16-row m-tiles in regs.
// Wave w covers nt = 4w..4w+3; B-chunk loaded once, reused for mt=0,1.
// ---------------------------------------------------------------------------
__device__ inline void stage1_relu2(const bf16x8 afr[2][4], short* Hs,
                                    const short* __restrict__ Waf,
                                    const float* __restrict__ ba,
                                    int w, int lane)
{
    const int row16 = lane & 15, g = lane >> 4;
    #pragma unroll
    for (int i = 0; i < 4; ++i) {
        int nt = w * 4 + i;
        bf16x8 bfr[4];
        #pragma unroll
        for (int ks = 0; ks < 4; ++ks)
            bfr[ks] = *reinterpret_cast<const bf16x8*>(
                Waf + ((size_t)(nt * 4 + ks) * 64 + lane) * 8);
        int col = nt * 16 + row16;
        float bias = ba[col];
        #pragma unroll
        for (int mt = 0; mt < 2; ++mt) {
            f32x4 acc = {0.f, 0.f, 0.f, 0.f};
            #pragma unroll
            for (int ks = 0; ks < 4; ++ks)
                acc = __builtin_amdgcn_mfma_f32_16x16x32_bf16(afr[mt][ks], bfr[ks], acc, 0, 0, 0);
            #pragma unroll
            for (int reg = 0; reg < 4; ++reg) {
                int hrow = mt * 16 + g * 4 + reg;
                float v = fmaxf(acc[reg] + bias, 0.0f);
                *reinterpret_cast<short*>(reinterpret_cast<char*>(Hs)
                    + hrow * 512 + ((((col >> 3) ^ hrow) & 31) * 16) + (col & 7) * 2) = f2bf(v);
            }
        }
    }
}

// ---------------------------------------------------------------------------
// Stage2: oacc[mt] += Hs(32x256) @ Wb(256x64); wave w owns col-tile nt=w,
// both m-tiles. B-chunk loaded once, reused for mt=0,1.
// ---------------------------------------------------------------------------
__device__ inline void stage2_acc2(const short* Hs, const short* __restrict__ Wbf,
                                   int w, int lane, f32x4 oacc[2])
{
    const int g = lane >> 4, row16 = lane & 15;
    #pragma unroll
    for (int ks = 0; ks < 8; ++ks) {
        bf16x8 b = *reinterpret_cast<const bf16x8*>(
            Wbf + ((size_t)(w * 8 + ks) * 64 + lane) * 8);
        #pragma unroll
        for (int mt = 0; mt < 2; ++mt) {
            int arow = mt * 16 + row16;
            bf16x8 a = *reinterpret_cast<const bf16x8*>(
                reinterpret_cast<const char*>(Hs)
                + arow * 512 + ((((ks * 4 + g) ^ arow) & 31) * 16));
            oacc[mt] = __builtin_amdgcn_mfma_f32_16x16x32_bf16(a, b, oacc[mt], 0, 0, 0);
        }
    }
}

// ---------------------------------------------------------------------------
// Fused kernel (32 rows/block, 4 waves):
//   gather-mean (2 nodes per wave in parallel, 8B/lane, 16 loads in flight)
//   Xs = Ms@Wsg; oacc = s2(relu(x@W1a+b1a),W1b) + s2(relu(Xs@W2a+b2a),W2b)
//   out = oacc + b1b + b2b  (single guarded store)
// ---------------------------------------------------------------------------
__global__ __launch_bounds__(256) void fused_kernel(
    const short* __restrict__ xb, const int* __restrict__ esrc,
    const int* __restrict__ deg,
    const short* __restrict__ Fsg,
    const short* __restrict__ F1a, const float* __restrict__ b1a,
    const short* __restrict__ F1b, const float* __restrict__ b1b,
    const short* __restrict__ F2a, const float* __restrict__ b2a,
    const short* __restrict__ F2b, const float* __restrict__ b2b,
    float* __restrict__ out)
{
    __shared__ short Ms[ROWS * 128];   // 8 KB
    __shared__ short Xs[ROWS * 128];   // 8 KB
    __shared__ short Hs[ROWS * 256];   // 16 KB
    const int t = threadIdx.x, w = t >> 6, lane = t & 63;
    const int l31 = lane & 31, half = lane >> 5;
    const int row16 = lane & 15, g = lane >> 4;
    const long r0 = (long)blockIdx.x * ROWS;

    // ---- gather-mean: wave w owns rows 8w..8w+7, processed as 4 pairs.
    //      lanes 0-31 -> even row (node A), lanes 32-63 -> odd row (node B).
    //      8B/lane (4 features); 16 row-loads in flight per chunk. ----
    #pragma unroll
    for (int p = 0; p < 4; ++p) {
        int rowA = w * 8 + p * 2;
        int myrow = rowA + half;
        long nodeA = r0 + rowA;
        int dv = deg[r0 + myrow]; dv = min(dv, SLOTS);
        int dA = __builtin_amdgcn_readlane(dv, 0);
        int dB = __builtin_amdgcn_readlane(dv, 32);
        int slot = lane < SLOTS ? lane : SLOTS - 1;
        int myA = esrc[(size_t)nodeA * SLOTS + slot];          // coalesced
        int myB = esrc[(size_t)(nodeA + 1) * SLOTS + slot];    // coalesced
        int dAm = max(dA - 1, 0), dBm = max(dB - 1, 0);
        int dmax = max(dA, dB);
        float a0 = 0.f, a1 = 0.f, a2 = 0.f, a3 = 0.f;
        for (int j = 0; j < dmax; j += 16) {
            uint2 u[16];
            #pragma unroll
            for (int k = 0; k < 16; ++k) {
                int kA = min(j + k, dAm), kB = min(j + k, dBm);
                int sA = __builtin_amdgcn_readlane(myA, kA);
                int sB = __builtin_amdgcn_readlane(myB, kB);
                sA = (dA > 0) ? sA : 0;                // sanitize garbage slots
                sB = (dB > 0) ? sB : 0;
                int s = half ? sB : sA;
                u[k] = *reinterpret_cast<const uint2*>(xb + (size_t)s * IN_F + l31 * 4);
            }
            #pragma unroll
            for (int k = 0; k < 16; ++k) {
                float wk = (j + k < dv) ? 1.0f : 0.0f;  // mask padded duplicates
                a0 = fmaf(bflo(u[k].x), wk, a0);
                a1 = fmaf(bfhi(u[k].x), wk, a1);
                a2 = fmaf(bflo(u[k].y), wk, a2);
                a3 = fmaf(bfhi(u[k].y), wk, a3);
            }
        }
        float inv = dv > 0 ? 1.0f / (float)dv : 0.0f;
        unsigned lo = (unsigned)(unsigned short)f2bf(a0 * inv)
                    | ((unsigned)(unsigned short)f2bf(a1 * inv) << 16);
        unsigned hi = (unsigned)(unsigned short)f2bf(a2 * inv)
                    | ((unsigned)(unsigned short)f2bf(a3 * inv) << 16);
        int chunk = ((l31 >> 1) ^ (myrow & 15)) & 15;
        uint2 pk; pk.x = lo; pk.y = hi;
        *reinterpret_cast<uint2*>(reinterpret_cast<char*>(Ms)
            + myrow * 256 + chunk * 16 + (l31 & 1) * 8) = pk;
    }
    __syncthreads();

    // ---- SAGE: Xs = Ms @ Wsg; wave w -> nt = 2w, 2w+1; mt reuse ----
    #pragma unroll
    for (int i = 0; i < 2; ++i) {
        int nt = w * 2 + i;
        bf16x8 bfr[4];
        #pragma unroll
        for (int ks = 0; ks < 4; ++ks)
            bfr[ks] = *reinterpret_cast<const bf16x8*>(
                Fsg + ((size_t)(nt * 4 + ks) * 64 + lane) * 8);
        #pragma unroll
        for (int mt = 0; mt < 2; ++mt) {
            f32x4 acc = {0.f, 0.f, 0.f, 0.f};
            #pragma unroll
            for (int ks = 0; ks < 4; ++ks) {
                int arow = mt * 16 + row16;
                bf16x8 a = *reinterpret_cast<const bf16x8*>(
                    reinterpret_cast<const char*>(Ms)
                    + arow * 256 + ((((ks * 4 + g) ^ arow) & 15) * 16));
                acc = __builtin_amdgcn_mfma_f32_16x16x32_bf16(a, bfr[ks], acc, 0, 0, 0);
            }
            int col = nt * 16 + row16;
            #pragma unroll
            for (int reg = 0; reg < 4; ++reg) {
                int xrow = mt * 16 + g * 4 + reg;
                *reinterpret_cast<short*>(reinterpret_cast<char*>(Xs)
                    + xrow * 256 + ((((col >> 3) ^ xrow) & 15) * 16) + (col & 7) * 2)
                    = f2bf(acc[reg]);
            }
        }
    }
    __syncthreads();

    // ---- branch 1 stage 1: A-frags (both m-tiles) from global xb ----
    {
        bf16x8 afr[2][4];
        #pragma unroll
        for (int mt = 0; mt < 2; ++mt) {
            const short* xrow = xb + (size_t)(r0 + mt * 16 + row16) * IN_F + g * 8;
            #pragma unroll
            for (int ks = 0; ks < 4; ++ks)
                afr[mt][ks] = *reinterpret_cast<const bf16x8*>(xrow + ks * 32);
        }
        stage1_relu2(afr, Hs, F1a, b1a, w, lane);
    }
    __syncthreads();

    // ---- branch 1 stage 2 -> register accumulators ----
    f32x4 oacc[2] = {{0.f, 0.f, 0.f, 0.f}, {0.f, 0.f, 0.f, 0.f}};
    stage2_acc2(Hs, F1b, w, lane, oacc);
    __syncthreads();                                   // before Hs overwrite

    // ---- branch 2 stage 1: A-frags from Xs ----
    {
        bf16x8 afr[2][4];
        #pragma unroll
        for (int mt = 0; mt < 2; ++mt) {
            int arow = mt * 16 + row16;
            #pragma unroll
            for (int ks = 0; ks < 4; ++ks)
                afr[mt][ks] = *reinterpret_cast<const bf16x8*>(
                    reinterpret_cast<const char*>(Xs)
                    + arow * 256 + ((((ks * 4 + g) ^ arow) & 15) * 16));
        }
        stage1_relu2(afr, Hs, F2a, b2a, w, lane);
    }
    __syncthreads();

    // ---- branch 2 stage 2 + single guarded store ----
    stage2_acc2(Hs, F2b, w, lane, oacc);
    {
        int col = w * 16 + row16;
        float bias = b1b[col] + b2b[col];
        #pragma unroll
        for (int mt = 0; mt < 2; ++mt)
            #pragma unroll
            for (int reg = 0; reg < 4; ++reg) {
                long row = r0 + mt * 16 + g * 4 + reg;
                if (row < N_NODES)
                    out[row * OUT_F + col] = oacc[mt][reg] + bias;
            }
    }
}

// ---------------------------------------------------------------------------
extern "C" void kernel_launch(void* const* d_in, const int* in_sizes, int n_in,
                              void* d_out, int out_size, void* d_ws, size_t ws_size,
                              hipStream_t stream)
{
    const float* x   = (const float*)d_in[0];
    const int*   ei  = (const int*)d_in[1];
    const float* Wsg = (const float*)d_in[2];
    const float* W1a = (const float*)d_in[3];
    const float* b1a = (const float*)d_in[4];
    const float* W1b = (const float*)d_in[5];
    const float* b1b = (const float*)d_in[6];
    const float* W2a = (const float*)d_in[7];
    const float* b2a = (const float*)d_in[8];
    const float* W2b = (const float*)d_in[9];
    const float* b2b = (const float*)d_in[10];
    float* out = (float*)d_out;

    // workspace layout (all 16B-aligned): ~24.45 MB total
    int* cursor = (int*)d_ws;                         // [N_PAD]
    int* esrc   = cursor + N_PAD;                     // [N_PAD*56] = 11.2 MB
    short* Fsg  = (short*)(esrc + (size_t)N_PAD * SLOTS);  // 2048 chunks
    short* F1a  = Fsg + 2048 * 8;                     // 4096 chunks
    short* F1b  = F1a + 4096 * 8;                     // 2048 chunks
    short* F2a  = F1b + 2048 * 8;                     // 4096 chunks
    short* F2b  = F2a + 4096 * 8;                     // 2048 chunks
    short* xb   = F2b + 2048 * 8;                     // [N_PAD*128] bf16

    hipMemsetAsync(cursor, 0, N_PAD * sizeof(int), stream);
    prep_build_kernel<<<5525, 256, 0, stream>>>(x, xb, Wsg, W1a, W1b, W2a, W2b,
                                                Fsg, F1a, F1b, F2a, F2b,
                                                ei, cursor, esrc);
    fused_kernel<<<NBLK, 256, 0, stream>>>(xb, esrc, cursor, Fsg,
                                           F1a, b1a, F1b, b1b,
                                           F2a, b2a, F2b, b2b, out);
}

// Round 7
// 119.637 us; speedup vs baseline: 1.0204x; 1.0204x over previous
//
#include <hip/hip_runtime.h>

#define N_NODES 50000
#define N_PAD   50048        // padded node count (tail reads defined, store guarded)
#define N_EDGES 600000
#define IN_F 128
#define HID 256
#define OUT_F 64
#define ROWS 16              // nodes per block; N_PAD/16 = 3128 blocks
#define SLOTS 56             // fixed bucket slots/node; P(deg>=56|Poisson(12))~1e-24
#define NBLK (N_PAD / ROWS)

typedef __attribute__((ext_vector_type(8))) short bf16x8;
typedef __attribute__((ext_vector_type(4))) float f32x4;

__device__ inline short f2bf(float f) {   // RNE float->bf16 bits
    unsigned u = __builtin_bit_cast(unsigned, f);
    u += 0x7fffu + ((u >> 16) & 1u);
    return (short)(u >> 16);
}
__device__ inline float bflo(unsigned u) { return __builtin_bit_cast(float, u << 16); }
__device__ inline float bfhi(unsigned u) { return __builtin_bit_cast(float, u & 0xffff0000u); }

// ---------------------------------------------------------------------------
// k0: Wc = W_sage @ W2a (fp32, 128x256), and zero cursor.
// blocks [0,128): row bid of Wc, thread t = col.  [128,324): zero cursor.
// ---------------------------------------------------------------------------
__global__ __launch_bounds__(256) void k0_kernel(
    const float* __restrict__ Wsg, const float* __restrict__ W2a,
    float* __restrict__ Wc, int* __restrict__ cursor)
{
    const int bid = blockIdx.x, t = threadIdx.x;
    if (bid < 128) {
        float acc = 0.f;
        #pragma unroll 8
        for (int j = 0; j < 128; ++j)
            acc = fmaf(Wsg[bid * 128 + j], W2a[j * 256 + t], acc);
        Wc[bid * 256 + t] = acc;
    } else {
        int i = (bid - 128) * 256 + t;
        if (i < N_PAD) cursor[i] = 0;
    }
}

// ---------------------------------------------------------------------------
// prep+build (one kernel, disjoint block ranges; cursor zeroed by k0):
//   [0,3125)      x fp32 -> bf16
//   [3125,3173)   weights -> bf16 B-fragment-major 16B chunks (F1a,F1b,Fc,F2b)
//   [3173,5517)   bucket fill: esrc[dst*56 + p] = (ushort)src; cursor ends as deg
// ---------------------------------------------------------------------------
__global__ __launch_bounds__(256) void prep_build_kernel(
    const float* __restrict__ x, short* __restrict__ xb,
    const float* __restrict__ W1a, const float* __restrict__ W1b,
    const float* __restrict__ Wc,  const float* __restrict__ W2b,
    short* __restrict__ F1a, short* __restrict__ F1b,
    short* __restrict__ Fc,  short* __restrict__ F2b,
    const int* __restrict__ ei, int* __restrict__ cursor,
    unsigned short* __restrict__ esrc)
{
    const int bid = blockIdx.x, t = threadIdx.x;
    if (bid < 3125) {
        int i = bid * 256 + t;                       // < 800000 exactly
        float4 a0 = *reinterpret_cast<const float4*>(x + (size_t)i * 8);
        float4 a1 = *reinterpret_cast<const float4*>(x + (size_t)i * 8 + 4);
        bf16x8 v;
        v[0] = f2bf(a0.x); v[1] = f2bf(a0.y); v[2] = f2bf(a0.z); v[3] = f2bf(a0.w);
        v[4] = f2bf(a1.x); v[5] = f2bf(a1.y); v[6] = f2bf(a1.z); v[7] = f2bf(a1.w);
        *reinterpret_cast<bf16x8*>(xb + (size_t)i * 8) = v;
    } else if (bid < 3173) {
        // chunk c: lane=c&63, ks=(c>>6)%KST, nt=(c>>6)/KST;
        //   elem j: B[ks*32 + (lane>>4)*8 + j][nt*16 + (lane&15)]
        int cid = (bid - 3125) * 256 + t;            // < 12288 exactly
        const float* src; short* dst; int N, KST, base;
        if      (cid < 4096)  { src = W1a; dst = F1a; N = 256; KST = 4; base = 0; }
        else if (cid < 6144)  { src = W1b; dst = F1b; N = 64;  KST = 8; base = 4096; }
        else if (cid < 10240) { src = Wc;  dst = Fc;  N = 256; KST = 4; base = 6144; }
        else                  { src = W2b; dst = F2b; N = 64;  KST = 8; base = 10240; }
        int c = cid - base;
        int lane = c & 63;
        int rem = c >> 6;
        int ks = rem % KST;
        int nt = rem / KST;
        int col = nt * 16 + (lane & 15);
        int k0 = ks * 32 + (lane >> 4) * 8;
        bf16x8 v;
        #pragma unroll
        for (int j = 0; j < 8; ++j)
            v[j] = f2bf(src[(size_t)(k0 + j) * N + col]);
        *reinterpret_cast<bf16x8*>(dst + (size_t)c * 8) = v;
    } else {
        int e = (bid - 3173) * 256 + t;
        if (e < N_EDGES) {
            int src = ei[e];
            int dst = ei[N_EDGES + e];
            int p = atomicAdd(&cursor[dst], 1);
            if (p < SLOTS) esrc[(size_t)dst * SLOTS + p] = (unsigned short)src;
        }
    }
}

// ---------------------------------------------------------------------------
// LDS tile helpers: [16][C] bf16 with 16B-chunk XOR swizzle (chunk ^= row)
// ---------------------------------------------------------------------------
__device__ inline bf16x8 afrag_lds128(const short* S, int lane, int ks) {
    int row = lane & 15, g = lane >> 4;
    int chunk = (ks * 4 + g) ^ row;            // 0..15
    return *reinterpret_cast<const bf16x8*>(
        reinterpret_cast<const char*>(S) + row * 256 + chunk * 16);
}
__device__ inline bf16x8 afrag_lds256(const short* S, int lane, int ks) {
    int row = lane & 15, g = lane >> 4;
    int chunk = (ks * 4 + g) ^ row;            // XOR flips low 4 bits, 0..31
    return *reinterpret_cast<const bf16x8*>(
        reinterpret_cast<const char*>(S) + row * 512 + chunk * 16);
}

// ---------------------------------------------------------------------------
// MFMA stages (16-row tile, 4 waves)
// stage1: Hs = relu(A @ Wa + ba) -> 16x256 bf16 swizzled LDS; wave w: nt=4w..4w+3
// stage2: acc += Hs(16x256) @ Wb(256x64); wave w: col-tile nt=w
// ---------------------------------------------------------------------------
__device__ inline void stage1_relu(const bf16x8 afr[4], short* Hs,
                                   const short* __restrict__ Waf,
                                   const float* __restrict__ ba,
                                   int w, int lane)
{
    const int row16 = lane & 15, g = lane >> 4;
    #pragma unroll
    for (int i = 0; i < 4; ++i) {
        int nt = w * 4 + i;
        f32x4 acc = {0.f, 0.f, 0.f, 0.f};
        #pragma unroll
        for (int ks = 0; ks < 4; ++ks) {
            bf16x8 b = *reinterpret_cast<const bf16x8*>(
                Waf + ((size_t)(nt * 4 + ks) * 64 + lane) * 8);
            acc = __builtin_amdgcn_mfma_f32_16x16x32_bf16(afr[ks], b, acc, 0, 0, 0);
        }
        int col = nt * 16 + row16;
        float bias = ba[col];
        #pragma unroll
        for (int reg = 0; reg < 4; ++reg) {
            int hrow = g * 4 + reg;
            float v = fmaxf(acc[reg] + bias, 0.0f);
            *reinterpret_cast<short*>(reinterpret_cast<char*>(Hs)
                + hrow * 512 + ((((col >> 3) ^ hrow) & 31) * 16) + (col & 7) * 2) = f2bf(v);
        }
    }
}

__device__ inline f32x4 stage2_acc(const short* Hs, const short* __restrict__ Wbf,
                                   int w, int lane, f32x4 acc)
{
    #pragma unroll
    for (int ks = 0; ks < 8; ++ks) {
        bf16x8 a = afrag_lds256(Hs, lane, ks);
        bf16x8 b = *reinterpret_cast<const bf16x8*>(
            Wbf + ((size_t)(w * 8 + ks) * 64 + lane) * 8);
        acc = __builtin_amdgcn_mfma_f32_16x16x32_bf16(a, b, acc, 0, 0, 0);
    }
    return acc;
}

// ---------------------------------------------------------------------------
// Fused kernel (16 rows/block, 4 waves, LDS 12 KB):
//   gather-mean -> Ms
//   oacc  = stage2(relu(Ms @ Wc + b2a), W2b)        [SAGE GEMM folded into Wc]
//   oacc += stage2(relu(x  @ W1a + b1a), W1b)
//   out = oacc + b1b + b2b   (single guarded store)
// ---------------------------------------------------------------------------
__global__ __launch_bounds__(256) void fused_kernel(
    const short* __restrict__ xb, const unsigned short* __restrict__ esrc,
    const int* __restrict__ deg,
    const short* __restrict__ F1a, const float* __restrict__ b1a,
    const short* __restrict__ F1b, const float* __restrict__ b1b,
    const short* __restrict__ Fc,  const float* __restrict__ b2a,
    const short* __restrict__ F2b, const float* __restrict__ b2b,
    float* __restrict__ out)
{
    __shared__ short Ms[16 * 128];   // 4 KB
    __shared__ short Hs[16 * 256];   // 8 KB
    const int t = threadIdx.x, w = t >> 6, lane = t & 63;
    const long r0 = (long)blockIdx.x * ROWS;
    const int row16 = lane & 15, g = lane >> 4;

    // ---- gather-mean: wave w owns rows w*4..+3; lane owns 2 features.
    //      16 row-loads in flight per chunk; ushort indices. ----
    #pragma unroll
    for (int nn = 0; nn < 4; ++nn) {
        int row = w * 4 + nn;
        long node = r0 + row;
        int d = deg[node]; d = min(d, SLOTS);
        int slot = min(lane, SLOTS - 1);
        int my = esrc[(size_t)node * SLOTS + slot];     // coalesced 2B/lane
        float ax = 0.f, ay = 0.f;
        for (int j = 0; j < d; j += 16) {
            unsigned u[16];
            #pragma unroll
            for (int k = 0; k < 16; ++k) {
                int cidx = min(j + k, d - 1);            // clamp: dup last row
                int s = __builtin_amdgcn_readlane(my, cidx);
                u[k] = *reinterpret_cast<const unsigned*>(xb + (size_t)s * IN_F + lane * 2);
            }
            #pragma unroll
            for (int k = 0; k < 16; ++k) {
                float wk = (j + k < d) ? 1.0f : 0.0f;    // mask padded dups
                ax = fmaf(bflo(u[k]), wk, ax);
                ay = fmaf(bfhi(u[k]), wk, ay);
            }
        }
        float inv = (d > 0) ? 1.0f / (float)d : 0.0f;
        ax *= inv; ay *= inv;
        int chunk = (lane >> 2) ^ row;                   // XOR swizzle
        unsigned packed = (unsigned)(unsigned short)f2bf(ax)
                        | ((unsigned)(unsigned short)f2bf(ay) << 16);
        *reinterpret_cast<unsigned*>(reinterpret_cast<char*>(Ms)
            + row * 256 + chunk * 16 + (lane & 3) * 4) = packed;
    }
    __syncthreads();

    // ---- branch 2 stage 1: Hs = relu(Ms @ Wc + b2a) ----
    {
        bf16x8 afr[4];
        #pragma unroll
        for (int ks = 0; ks < 4; ++ks) afr[ks] = afrag_lds128(Ms, lane, ks);
        stage1_relu(afr, Hs, Fc, b2a, w, lane);
    }
    __syncthreads();

    // ---- branch 2 stage 2 -> register accumulator ----
    f32x4 oacc = {0.f, 0.f, 0.f, 0.f};
    oacc = stage2_acc(Hs, F2b, w, lane, oacc);
    __syncthreads();                                     // before Hs overwrite

    // ---- branch 1 stage 1: Hs = relu(x @ W1a + b1a), A-frags from global xb ----
    {
        bf16x8 afr[4];
        const short* xrow = xb + (size_t)(r0 + row16) * IN_F + g * 8;
        #pragma unroll
        for (int ks = 0; ks < 4; ++ks)
            afr[ks] = *reinterpret_cast<const bf16x8*>(xrow + ks * 32);
        stage1_relu(afr, Hs, F1a, b1a, w, lane);
    }
    __syncthreads();

    // ---- branch 1 stage 2 + single guarded store ----
    oacc = stage2_acc(Hs, F1b, w, lane, oacc);
    {
        int col = w * 16 + row16;
        float bias = b1b[col] + b2b[col];
        #pragma unroll
        for (int reg = 0; reg < 4; ++reg) {
            long row = r0 + g * 4 + reg;
            if (row < N_NODES)
                out[row * OUT_F + col] = oacc[reg] + bias;
        }
    }
}

// ---------------------------------------------------------------------------
extern "C" void kernel_launch(void* const* d_in, const int* in_sizes, int n_in,
                              void* d_out, int out_size, void* d_ws, size_t ws_size,
                              hipStream_t stream)
{
    const float* x   = (const float*)d_in[0];
    const int*   ei  = (const int*)d_in[1];
    const float* Wsg = (const float*)d_in[2];
    const float* W1a = (const float*)d_in[3];
    const float* b1a = (const float*)d_in[4];
    const float* W1b = (const float*)d_in[5];
    const float* b1b = (const float*)d_in[6];
    const float* W2a = (const float*)d_in[7];
    const float* b2a = (const float*)d_in[8];
    const float* W2b = (const float*)d_in[9];
    const float* b2b = (const float*)d_in[10];
    float* out = (float*)d_out;

    // workspace layout (all 16B-aligned): ~18.9 MB total
    int* cursor = (int*)d_ws;                              // [N_PAD] (200 KB)
    unsigned short* esrc = (unsigned short*)(cursor + N_PAD);  // [N_PAD*56] = 5.6 MB
    float* Wc  = (float*)(esrc + (size_t)N_PAD * SLOTS);   // [128*256] fp32 (128 KB)
    short* F1a = (short*)(Wc + 128 * 256);                 // 4096 chunks (64 KB)
    short* F1b = F1a + 4096 * 8;                           // 2048 chunks (32 KB)
    short* Fc  = F1b + 2048 * 8;                           // 4096 chunks (64 KB)
    short* F2b = Fc + 4096 * 8;                            // 2048 chunks (32 KB)
    short* xb  = F2b + 2048 * 8;                           // [N_PAD*128] bf16 (12.8 MB)

    k0_kernel<<<324, 256, 0, stream>>>(Wsg, W2a, Wc, cursor);
    prep_build_kernel<<<5517, 256, 0, stream>>>(x, xb, W1a, W1b, Wc, W2b,
                                                F1a, F1b, Fc, F2b,
                                                ei, cursor, esrc);
    fused_kernel<<<NBLK, 256, 0, stream>>>(xb, esrc, cursor,
                                           F1a, b1a, F1b, b1b,
                                           Fc, b2a, F2b, b2b, out);
}